// Round 10
// baseline (315.218 us; speedup 1.0000x reference)
//
#include <hip/hip_runtime.h>

#define HSZ 64
#define ISZ 8
#define TSZ 512
#define BTILE 8    // batch rows per block -> 512 blocks = 2 independent blocks/CU
#define NW 8       // waves per block (512 threads)
#define KP 104     // k per row: [0,64) h | [64,72) x | [72,96) zero pad | tail pad

typedef _Float16 f16;
typedef __attribute__((ext_vector_type(8))) _Float16 f16x8;
typedef __attribute__((ext_vector_type(4))) float f32x4;
typedef unsigned short u16;

__device__ __forceinline__ u16 f16bits(float f) {
    union { f16 h; u16 u; } v; v.h = (f16)f;
    return v.u;
}

// Operand-swapped MFMA LSTM, 2 anti-phased blocks per CU.
// A = weights (M = 16 gate rows), B = h/x (N = 16 batch cols, 8 valid).
// Wave w owns tiles q=0,1 -> hidden units 8w+4q+lg. Lane (lr,lg) holds all 4
// gates of units (batch lr, hidden 8w+lg) and (batch lr, hidden 8w+4+lg) in
// acc0/acc1 -> act fully lane-local. Bias = MFMA C-in (pre-scaled by -log2e /
// -2log2e). Batch cols 8-15 are phantom (zero-init h/x, finite forever, never
// read back). One barrier per step; the CU's two blocks drift out of phase so
// one block's act (VALU) overlaps the other's DS/MFMA phases.
__global__ __launch_bounds__(512, 4) void lstm_dual(
    const float* __restrict__ x,      // [B, T, I]
    const float* __restrict__ W_ih,   // [4H, I]
    const float* __restrict__ W_hh,   // [4H, H]
    const float* __restrict__ b_ih,   // [4H]
    const float* __restrict__ b_hh,   // [4H]
    const float* __restrict__ W_fc,   // [O, H]
    const float* __restrict__ b_fc,   // [O]
    float* __restrict__ out)          // [B, O]
{
    const int tid = threadIdx.x;
    const int w  = tid >> 6;          // wave 0..7, owns hidden units [8w, 8w+8)
    const int l  = tid & 63;
    const int lr = l & 15;            // A: M-row sel / B,C: batch col
    const int lg = l >> 4;            // k-group
    const int B0 = blockIdx.x * BTILE;

    __shared__ __align__(16) u16 H[2][16][KP];   // [buf][batch col][k]
    __shared__ float red[NW][16];

    for (int i = tid; i < 2 * 16 * KP; i += 512)
        ((u16*)H)[i] = 0;

    // ---- A-fragments (weights) for 2 tiles, pre-scaled; bias as C-in ----
    const int gate = lr & 3;
    const float sc = (gate == 2) ? -2.885390082f : -1.442695041f;
    f16x8 wa0[2], wa1[2], wa2[2];
    f32x4 bias4[2];
#pragma unroll
    for (int q = 0; q < 2; ++q) {
        const int n  = 2 * w + q;                    // tile index 0..15
        const int gc = gate * HSZ + 4 * n + (lr >> 2);  // gate row in [0,256)
        {
            const float4 a = *reinterpret_cast<const float4*>(&W_hh[gc * HSZ + lg * 8]);
            const float4 b = *reinterpret_cast<const float4*>(&W_hh[gc * HSZ + lg * 8 + 4]);
            wa0[q][0] = (f16)(sc * a.x); wa0[q][1] = (f16)(sc * a.y);
            wa0[q][2] = (f16)(sc * a.z); wa0[q][3] = (f16)(sc * a.w);
            wa0[q][4] = (f16)(sc * b.x); wa0[q][5] = (f16)(sc * b.y);
            wa0[q][6] = (f16)(sc * b.z); wa0[q][7] = (f16)(sc * b.w);
        }
        {
            const float4 a = *reinterpret_cast<const float4*>(&W_hh[gc * HSZ + 32 + lg * 8]);
            const float4 b = *reinterpret_cast<const float4*>(&W_hh[gc * HSZ + 32 + lg * 8 + 4]);
            wa1[q][0] = (f16)(sc * a.x); wa1[q][1] = (f16)(sc * a.y);
            wa1[q][2] = (f16)(sc * a.z); wa1[q][3] = (f16)(sc * a.w);
            wa1[q][4] = (f16)(sc * b.x); wa1[q][5] = (f16)(sc * b.y);
            wa1[q][6] = (f16)(sc * b.z); wa1[q][7] = (f16)(sc * b.w);
        }
#pragma unroll
        for (int j = 0; j < 8; ++j) wa2[q][j] = (f16)0.0f;
        if (lg == 0) {                // k 64..71 -> x weights; zero for lg>=1
            const float4 a = *reinterpret_cast<const float4*>(&W_ih[gc * ISZ]);
            const float4 b = *reinterpret_cast<const float4*>(&W_ih[gc * ISZ + 4]);
            wa2[q][0] = (f16)(sc * a.x); wa2[q][1] = (f16)(sc * a.y);
            wa2[q][2] = (f16)(sc * a.z); wa2[q][3] = (f16)(sc * a.w);
            wa2[q][4] = (f16)(sc * b.x); wa2[q][5] = (f16)(sc * b.y);
            wa2[q][6] = (f16)(sc * b.z); wa2[q][7] = (f16)(sc * b.w);
        }
        const int hc = 4 * n + lg;    // this tile's hidden unit for this lane
#pragma unroll
        for (int r = 0; r < 4; ++r) {
            const float s = (r == 2) ? -2.885390082f : -1.442695041f;
            bias4[q][r] = s * (b_ih[r * HSZ + hc] + b_hh[r * HSZ + hc]);
        }
    }

    __syncthreads();  // zeroing visible

    // stage x(0): wave 0, lane l -> batch row l>>3 (0..7), input l&7
    const float* xptr = x + (size_t)(B0 + (l >> 3)) * TSZ * ISZ + (l & 7);
    if (w == 0)
        H[0][l >> 3][HSZ + (l & 7)] = f16bits(xptr[0]);
    __syncthreads();

    // hoisted LDS offsets (u16 units)
    const u16* rd0 = &H[0][lr][lg * 8];
    const u16* rd1 = &H[1][lr][lg * 8];
    const int hcol0 = 8 * w + lg, hcol1 = 8 * w + 4 + lg;
    u16* wrA0 = &H[0][lr][hcol0];  u16* wrA1 = &H[0][lr][hcol1];
    u16* wrB0 = &H[1][lr][hcol0];  u16* wrB1 = &H[1][lr][hcol1];
    u16* xsA  = &H[0][l >> 3][HSZ + (l & 7)];
    u16* xsB  = &H[1][l >> 3][HSZ + (l & 7)];

    float c0 = 0.f, c1 = 0.f, h0 = 0.f, h1 = 0.f;
    const float L2 = 2.885390082f;

#define ACT(ACC, CC, HH)                                                       \
    {                                                                          \
        const float ea = __builtin_amdgcn_exp2f((ACC)[0]);                     \
        const float eb = __builtin_amdgcn_exp2f((ACC)[1]);                     \
        const float ed = __builtin_amdgcn_exp2f((ACC)[2]);                     \
        const float es = __builtin_amdgcn_exp2f((ACC)[3]);                     \
        const float A1 = 1.0f + ea, B1 = 1.0f + eb, D1 = 1.0f + ed;            \
        const float R1 = __builtin_amdgcn_rcpf(A1 * B1 * D1);                  \
        CC = fmaf(CC * A1, D1, (1.0f - ed) * B1) * R1;                         \
        const float eu = __builtin_amdgcn_exp2f(-L2 * CC);                     \
        const float R2 = __builtin_amdgcn_rcpf((1.0f + es) * (1.0f + eu));     \
        HH = (1.0f - eu) * R2;                                                 \
    }

#define STEP(RD, WR0, WR1, XS, XIDX, XGUARD)                                   \
    {                                                                          \
        float xv = 0.0f;                                                       \
        if ((w == 0) && (XGUARD))                                              \
            xv = xptr[(size_t)(XIDX) * ISZ];                                   \
        const f16x8 b0 = *reinterpret_cast<const f16x8*>(RD);                  \
        const f16x8 b1 = *reinterpret_cast<const f16x8*>(RD + 32);             \
        f16x8 b2 = {};                                                         \
        if (lg == 0)                                                           \
            b2 = *reinterpret_cast<const f16x8*>(RD + 64);                     \
        f32x4 a0 = __builtin_amdgcn_mfma_f32_16x16x32_f16(wa2[0], b2, bias4[0], 0, 0, 0); \
        f32x4 a1 = __builtin_amdgcn_mfma_f32_16x16x32_f16(wa2[1], b2, bias4[1], 0, 0, 0); \
        a0 = __builtin_amdgcn_mfma_f32_16x16x32_f16(wa0[0], b0, a0, 0, 0, 0);  \
        a1 = __builtin_amdgcn_mfma_f32_16x16x32_f16(wa0[1], b0, a1, 0, 0, 0);  \
        a0 = __builtin_amdgcn_mfma_f32_16x16x32_f16(wa1[0], b1, a0, 0, 0, 0);  \
        a1 = __builtin_amdgcn_mfma_f32_16x16x32_f16(wa1[1], b1, a1, 0, 0, 0);  \
        ACT(a0, c0, h0)                                                        \
        ACT(a1, c1, h1)                                                        \
        *(WR0) = f16bits(h0);                                                  \
        *(WR1) = f16bits(h1);                                                  \
        if ((w == 0) && (XGUARD))                                              \
            *(XS) = f16bits(xv);                                               \
        __syncthreads();                                                       \
    }

    for (int t = 0; t < TSZ; t += 2) {
        // step t: read buf0, write h/x into buf1. x(t+1) always exists.
        STEP(rd0, wrB0, wrB1, xsB, t + 1, true)
        // step t+1: read buf1, write into buf0. x(t+2) exists unless t == 510.
        STEP(rd1, wrA0, wrA1, xsA, t + 2, t < TSZ - 2)
    }
#undef STEP
#undef ACT

    // ---- final FC: out[b] = sum_h h(b,hu) * W_fc[hu] + b_fc ----
    float v = h0 * W_fc[hcol0] + h1 * W_fc[hcol1];
    v += __shfl_xor(v, 16);
    v += __shfl_xor(v, 32);           // sum over lg -> per batch col lr
    if (lg == 0) red[w][lr] = v;
    __syncthreads();
    if (tid < BTILE) {
        float s = b_fc[0];
#pragma unroll
        for (int ww = 0; ww < NW; ++ww) s += red[ww][tid];
        out[B0 + tid] = s;
    }
}

extern "C" void kernel_launch(void* const* d_in, const int* in_sizes, int n_in,
                              void* d_out, int out_size, void* d_ws, size_t ws_size,
                              hipStream_t stream) {
    const float* x    = (const float*)d_in[0];
    const float* W_ih = (const float*)d_in[1];
    const float* W_hh = (const float*)d_in[2];
    const float* b_ih = (const float*)d_in[3];
    const float* b_hh = (const float*)d_in[4];
    const float* W_fc = (const float*)d_in[5];
    const float* b_fc = (const float*)d_in[6];
    float* out = (float*)d_out;

    const int B = in_sizes[0] / (TSZ * ISZ);  // 4096
    lstm_dual<<<B / BTILE, NW * 64, 0, stream>>>(x, W_ih, W_hh, b_ih, b_hh, W_fc, b_fc, out);
}

// Round 11
// 258.589 us; speedup vs baseline: 1.2190x; 1.2190x over previous
//
#include <hip/hip_runtime.h>

#define HSZ 64
#define ISZ 8
#define TSZ 512
#define BTILE 8    // batch rows per block -> 512 blocks = 2 anti-phased blocks/CU
#define NW 8       // waves per block (512 threads)
#define KP 104     // k per row: [0,64) h | [64,72) x | zero pad; 208B row stride

typedef _Float16 f16;
typedef __attribute__((ext_vector_type(8))) _Float16 f16x8;
typedef __attribute__((ext_vector_type(4))) float f32x4;
typedef unsigned short u16;

__device__ __forceinline__ u16 f16bits(float f) {
    union { f16 h; u16 u; } v; v.h = (f16)f;
    return v.u;
}

// Operand-swapped MFMA LSTM, 2 anti-phased blocks/CU, xor8 act-redistribution.
// A = weights (M = 16 gate rows), B = h/x (N = 16 batch cols, 8 valid).
// Wave w computes 2 gate-tiles (hidden 8w+lg and 8w+4+lg) sharing one B-read.
// After MFMA, lane lr>=8 pulls tile-1's acc from lane lr-8 (shfl_xor 8) so each
// lane activates exactly ONE valid unit: no duplicate act (r10's regression).
// Bias = MFMA C-in, pre-scaled by -log2e / -2log2e. One barrier per step.
// Batch cols 8-15 phantom: zero forever, their C-cols are discarded.
__global__ __launch_bounds__(512, 4) void lstm_dual2(
    const float* __restrict__ x,      // [B, T, I]
    const float* __restrict__ W_ih,   // [4H, I]
    const float* __restrict__ W_hh,   // [4H, H]
    const float* __restrict__ b_ih,   // [4H]
    const float* __restrict__ b_hh,   // [4H]
    const float* __restrict__ W_fc,   // [O, H]
    const float* __restrict__ b_fc,   // [O]
    float* __restrict__ out)          // [B, O]
{
    const int tid = threadIdx.x;
    const int w  = tid >> 6;          // wave 0..7, owns hidden units [8w, 8w+8)
    const int l  = tid & 63;
    const int lr = l & 15;            // A: M-row sel / B,C: batch col
    const int lg = l >> 4;            // k-group
    const int B0 = blockIdx.x * BTILE;
    const bool lo8 = (lr < 8);

    __shared__ __align__(16) u16 H[2][16][KP];   // [buf][batch col][k]
    __shared__ float red[NW][BTILE];

    for (int i = tid; i < 2 * 16 * KP; i += 512)
        ((u16*)H)[i] = 0;

    // ---- A-fragments (weights) for 2 tiles, pre-scaled; bias as C-in ----
    const int gate = lr & 3;
    const float sc = (gate == 2) ? -2.885390082f : -1.442695041f;
    f16x8 wa0[2], wa1[2], wa2[2];
    f32x4 bias4[2];
#pragma unroll
    for (int q = 0; q < 2; ++q) {
        const int n  = 2 * w + q;                       // tile index 0..15
        const int gc = gate * HSZ + 4 * n + (lr >> 2);  // gate row in [0,256)
        {
            const float4 a = *reinterpret_cast<const float4*>(&W_hh[gc * HSZ + lg * 8]);
            const float4 b = *reinterpret_cast<const float4*>(&W_hh[gc * HSZ + lg * 8 + 4]);
            wa0[q][0] = (f16)(sc * a.x); wa0[q][1] = (f16)(sc * a.y);
            wa0[q][2] = (f16)(sc * a.z); wa0[q][3] = (f16)(sc * a.w);
            wa0[q][4] = (f16)(sc * b.x); wa0[q][5] = (f16)(sc * b.y);
            wa0[q][6] = (f16)(sc * b.z); wa0[q][7] = (f16)(sc * b.w);
        }
        {
            const float4 a = *reinterpret_cast<const float4*>(&W_hh[gc * HSZ + 32 + lg * 8]);
            const float4 b = *reinterpret_cast<const float4*>(&W_hh[gc * HSZ + 32 + lg * 8 + 4]);
            wa1[q][0] = (f16)(sc * a.x); wa1[q][1] = (f16)(sc * a.y);
            wa1[q][2] = (f16)(sc * a.z); wa1[q][3] = (f16)(sc * a.w);
            wa1[q][4] = (f16)(sc * b.x); wa1[q][5] = (f16)(sc * b.y);
            wa1[q][6] = (f16)(sc * b.z); wa1[q][7] = (f16)(sc * b.w);
        }
#pragma unroll
        for (int j = 0; j < 8; ++j) wa2[q][j] = (f16)0.0f;
        if (lg == 0) {                // k 64..71 -> x weights; zero for lg>=1
            const float4 a = *reinterpret_cast<const float4*>(&W_ih[gc * ISZ]);
            const float4 b = *reinterpret_cast<const float4*>(&W_ih[gc * ISZ + 4]);
            wa2[q][0] = (f16)(sc * a.x); wa2[q][1] = (f16)(sc * a.y);
            wa2[q][2] = (f16)(sc * a.z); wa2[q][3] = (f16)(sc * a.w);
            wa2[q][4] = (f16)(sc * b.x); wa2[q][5] = (f16)(sc * b.y);
            wa2[q][6] = (f16)(sc * b.z); wa2[q][7] = (f16)(sc * b.w);
        }
        const int hc = 4 * n + lg;    // tile q's hidden unit for this lane
#pragma unroll
        for (int r = 0; r < 4; ++r) {
            const float s = (r == 2) ? -2.885390082f : -1.442695041f;
            bias4[q][r] = s * (b_ih[r * HSZ + hc] + b_hh[r * HSZ + hc]);
        }
    }

    __syncthreads();  // zeroing visible

    // stage x(0): wave 0, lane l -> batch row l>>3 (0..7), input l&7
    const float* xptr = x + (size_t)(B0 + (l >> 3)) * TSZ * ISZ + (l & 7);
    if (w == 0)
        H[0][l >> 3][HSZ + (l & 7)] = f16bits(xptr[0]);
    __syncthreads();

    // this lane's owned unit after xor8 redistribution:
    const int hcol = 8 * w + lg + (lo8 ? 0 : 4);
    const int brow = lr & 7;
    // hoisted LDS offsets
    const u16* rd0 = &H[0][lr][lg * 8];
    const u16* rd1 = &H[1][lr][lg * 8];
    u16* wrA = &H[0][brow][hcol];
    u16* wrB = &H[1][brow][hcol];
    u16* xsA = &H[0][l >> 3][HSZ + (l & 7)];
    u16* xsB = &H[1][l >> 3][HSZ + (l & 7)];

    float c = 0.0f, h = 0.0f;
    const float L2 = 2.885390082f;

#define STEP(RD, WR, XS, XIDX, XGUARD)                                         \
    {                                                                          \
        float xv = 0.0f;                                                       \
        if ((w == 0) && (XGUARD))                                              \
            xv = xptr[(size_t)(XIDX) * ISZ];                                   \
        const f16x8 b0 = *reinterpret_cast<const f16x8*>(RD);                  \
        const f16x8 b1 = *reinterpret_cast<const f16x8*>(RD + 32);             \
        f16x8 b2 = {};                                                         \
        if (lg == 0)                                                           \
            b2 = *reinterpret_cast<const f16x8*>(RD + 64);                     \
        f32x4 a0 = __builtin_amdgcn_mfma_f32_16x16x32_f16(wa2[0], b2, bias4[0], 0, 0, 0); \
        f32x4 a1 = __builtin_amdgcn_mfma_f32_16x16x32_f16(wa2[1], b2, bias4[1], 0, 0, 0); \
        a0 = __builtin_amdgcn_mfma_f32_16x16x32_f16(wa0[0], b0, a0, 0, 0, 0);  \
        a1 = __builtin_amdgcn_mfma_f32_16x16x32_f16(wa0[1], b0, a1, 0, 0, 0);  \
        a0 = __builtin_amdgcn_mfma_f32_16x16x32_f16(wa1[0], b1, a0, 0, 0, 0);  \
        a1 = __builtin_amdgcn_mfma_f32_16x16x32_f16(wa1[1], b1, a1, 0, 0, 0);  \
        float p0, p1, p2, p3;                                                  \
        {                                                                      \
            const float s0 = __shfl_xor(a1[0], 8);                             \
            const float s1 = __shfl_xor(a1[1], 8);                             \
            const float s2 = __shfl_xor(a1[2], 8);                             \
            const float s3 = __shfl_xor(a1[3], 8);                             \
            p0 = lo8 ? a0[0] : s0;                                             \
            p1 = lo8 ? a0[1] : s1;                                             \
            p2 = lo8 ? a0[2] : s2;                                             \
            p3 = lo8 ? a0[3] : s3;                                             \
        }                                                                      \
        const float ea = __builtin_amdgcn_exp2f(p0);                           \
        const float eb = __builtin_amdgcn_exp2f(p1);                           \
        const float ed = __builtin_amdgcn_exp2f(p2);                           \
        const float es = __builtin_amdgcn_exp2f(p3);                           \
        const float A1 = 1.0f + ea, B1 = 1.0f + eb, D1 = 1.0f + ed;            \
        const float R1 = __builtin_amdgcn_rcpf(A1 * B1 * D1);                  \
        c = fmaf(c * A1, D1, (1.0f - ed) * B1) * R1;                           \
        const float eu = __builtin_amdgcn_exp2f(-L2 * c);                      \
        const float R2 = __builtin_amdgcn_rcpf((1.0f + es) * (1.0f + eu));     \
        h = (1.0f - eu) * R2;                                                  \
        *(WR) = f16bits(h);                                                    \
        if ((w == 0) && (XGUARD))                                              \
            *(XS) = f16bits(xv);                                               \
        __syncthreads();                                                       \
    }

    for (int t = 0; t < TSZ; t += 2) {
        // step t: read buf0, write h/x into buf1. x(t+1) always exists.
        STEP(rd0, wrB, xsB, t + 1, true)
        // step t+1: read buf1, write into buf0. x(t+2) exists unless t == 510.
        STEP(rd1, wrA, xsA, t + 2, t < TSZ - 2)
    }
#undef STEP

    // ---- final FC: out[b] = sum_h h(b,hu) * W_fc[hu] + b_fc ----
    // lane's unit: (batch brow, hidden hcol). xor8 pairs same batch; xor16/32 sum lg.
    float v = h * W_fc[hcol];
    v += __shfl_xor(v, 8);
    v += __shfl_xor(v, 16);
    v += __shfl_xor(v, 32);
    if (l < 8) red[w][l] = v;
    __syncthreads();
    if (tid < BTILE) {
        float s = b_fc[0];
#pragma unroll
        for (int ww = 0; ww < NW; ++ww) s += red[ww][tid];
        out[B0 + tid] = s;
    }
}

extern "C" void kernel_launch(void* const* d_in, const int* in_sizes, int n_in,
                              void* d_out, int out_size, void* d_ws, size_t ws_size,
                              hipStream_t stream) {
    const float* x    = (const float*)d_in[0];
    const float* W_ih = (const float*)d_in[1];
    const float* W_hh = (const float*)d_in[2];
    const float* b_ih = (const float*)d_in[3];
    const float* b_hh = (const float*)d_in[4];
    const float* W_fc = (const float*)d_in[5];
    const float* b_fc = (const float*)d_in[6];
    float* out = (float*)d_out;

    const int B = in_sizes[0] / (TSZ * ISZ);  // 4096
    lstm_dual2<<<B / BTILE, NW * 64, 0, stream>>>(x, W_ih, W_hh, b_ih, b_hh, W_fc, b_fc, out);
}